// Round 13
// baseline (609.832 us; speedup 1.0000x reference)
//
#include <hip/hip_runtime.h>

namespace {

constexpr int kN  = 32;
constexpr int kC  = 512;
constexpr int kH  = 32;
constexpr int kW  = 32;
constexpr int kHW = kH * kW;

// bf16 chunked-padded activation layout: [n][chunk=ci/32][34 rows][34 cols][32 ci]
constexpr int PCH   = 36992;                 // 34*34*32 elems per (n,chunk) plane
constexpr size_t WTF_ELEMS = (size_t)9 * kC * kC;          // 2,359,296 bf16
constexpr size_t XH_ELEMS  = (size_t)kN * 16 * PCH;        // 18,939,904 bf16
constexpr size_t QKV_ELEMS = (size_t)kN * kHW * kC;        // 16,777,216 bf16

using bf16x8 = __attribute__((ext_vector_type(8))) short;
using bf16x4 = __attribute__((ext_vector_type(4))) short;
using f32x4  = __attribute__((ext_vector_type(4))) float;

__device__ __forceinline__ float bf2f(short s) {
  unsigned u = ((unsigned)(unsigned short)s) << 16;
  return __builtin_bit_cast(float, u);
}
__device__ __forceinline__ short f2bf(float f) {
  unsigned u = __builtin_bit_cast(unsigned, f);
  u += 0x7FFFu + ((u >> 16) & 1u);
  return (short)(u >> 16);
}
__device__ __forceinline__ void gload_lds16(const void* g, void* l) {
  __builtin_amdgcn_global_load_lds(
      (const __attribute__((address_space(1))) void*)g,
      (__attribute__((address_space(3))) void*)l, 16, 0, 0);
}

// ---- weight pack: w[co][ci][3][3] f32 -> wtf[t][kk][nnG][lane][8] bf16 ----
__global__ __launch_bounds__(256) void wtf_pack_kernel(
    const float* __restrict__ w, short* __restrict__ wtf) {
  __shared__ float tile[32][289];  // [co][ci*9+t]
  const int co0 = blockIdx.x * 32;
  const int ci0 = blockIdx.y * 32;
  for (int idx = threadIdx.x; idx < 32 * 288; idx += 256) {
    int c = idx % 288, r = idx / 288;
    tile[r][c] = w[(size_t)(co0 + r) * (kC * 9) + (size_t)ci0 * 9 + c];
  }
  __syncthreads();
  const int kkb  = ci0 >> 5;
  const int nnG0 = co0 >> 4;
  for (int g = threadIdx.x; g < 9 * 2 * 64; g += 256) {
    int laneg = g & 63;
    int nnL   = (g >> 6) & 1;
    int t     = g >> 7;  // 0..8
    int hi    = laneg >> 4;
    int coL   = nnL * 16 + (laneg & 15);
    bf16x8 pk;
#pragma unroll
    for (int j = 0; j < 8; ++j) pk[j] = f2bf(tile[coL][(hi * 8 + j) * 9 + t]);
    *(bf16x8*)&wtf[(((size_t)t * 16 + kkb) * 32 + nnG0 + nnL) * 512 + laneg * 8] = pk;
  }
}

// ---- x NCHW f32 -> xh chunked-padded bf16 ---------------------------------
__global__ __launch_bounds__(256) void x2xh_kernel(
    const float* __restrict__ x, short* __restrict__ xh) {
  __shared__ float tile[32][33];  // [w][ci]
  const int ch = blockIdx.x;   // 0..15
  const int h  = blockIdx.y;   // 0..31
  const int n  = blockIdx.z;   // 0..31
  const int w0 = threadIdx.x & 31;
  const int c0 = threadIdx.x >> 5;
#pragma unroll
  for (int pass = 0; pass < 4; ++pass) {
    int cir = pass * 8 + c0;
    tile[w0][cir] = x[(((size_t)n * kC + ch * 32 + cir) * kH + h) * kW + w0];
  }
  __syncthreads();
  const int wv = threadIdx.x >> 3;
  const int g4 = (threadIdx.x & 7) * 4;
  bf16x4 pk;
#pragma unroll
  for (int j = 0; j < 4; ++j) pk[j] = f2bf(tile[wv][g4 + j]);
  *(bf16x4*)&xh[(((size_t)n * 16 + ch) * 1156 + (size_t)(h + 1) * 34 + (wv + 1)) * 32 + g4] = pk;
}

// ---- FUSED q/k/v conv3x3 via MFMA implicit shift-GEMM ---------------------
// Wave tiling: each wave owns a DISTINCT 16-co quarter x all 128 sp (R12).
// NEW: A-slab bank-conflict swizzle (T2 / rule #21). LDS slot (pos, g)
// [g = 16B sub-slot 0..3 of the 64B row] holds global data (pos, g^(pos&3)):
//   - staging: per-lane GLOBAL source permuted (slot s loads
//     (s&~3)|((s&3)^((s>>2)&3))); LDS dest stays linear (HW requirement).
//   - read: a-frag (pb, lhi) found at sub-slot lhi^(pb&3).
// Spreads the 16-row column read over 4x more bank groups (was 8-way).
__global__ __launch_bounds__(256, 2) void conv_qkv_kernel(
    const short* __restrict__ xin,
    const short* __restrict__ wtq, const short* __restrict__ wtk,
    const short* __restrict__ wtv,
    short* __restrict__ outq, short* __restrict__ outk,
    short* __restrict__ outv) {
  __shared__ __align__(16) short As[3][8192];  // [pos 256][ci 32] bf16, x3
  const int tid  = threadIdx.x;
  const int lane = tid & 63;
  const int l15  = lane & 15, lhi = lane >> 4;
  const int w    = tid >> 6;       // wave 0..3 = co quarter
  const int wbase = tid & 192;

  const int xcd = blockIdx.x & 7;
  const int m   = blockIdx.x >> 3;
  const int co0 = (m >> 5) * 64;
  const int spt = m & 7;
  const int n   = xcd * 4 + ((m >> 3) & 3);
  const int h0  = spt * 4;
  const int sp0 = spt * 128;

  const short* srcA = xin + (size_t)n * (16 * PCH) + (size_t)h0 * (34 * 32);
  const size_t boff = ((size_t)(co0 >> 4) + w) * 512 + lane * 8;
  const short* bp[3] = {wtq + boff, wtk + boff, wtv + boff};

  f32x4 acc[3][8];
#pragma unroll
  for (int c = 0; c < 3; ++c)
#pragma unroll
    for (int mf = 0; mf < 8; ++mf)
#pragma unroll
      for (int r = 0; r < 4; ++r) acc[c][mf][r] = 0.f;

  // swizzled per-lane source slot for each staging pass (slot = pass*256+tid)
  int ssrc[4];
#pragma unroll
  for (int pass = 0; pass < 4; ++pass) {
    int s = pass * 256 + tid;
    ssrc[pass] = (s & ~3) | ((s & 3) ^ ((s >> 2) & 3));
  }

#define STAGE_A(kk, buf)                                                      \
  {                                                                           \
    const short* gA = srcA + (size_t)(kk) * PCH;                              \
    _Pragma("unroll") for (int pass = 0; pass < 4; ++pass)                    \
        gload_lds16(gA + (size_t)ssrc[pass] * 8,                              \
                    &As[buf][(pass * 256 + wbase) * 8]);                      \
  }

  STAGE_A(0, 0);
  STAGE_A(1, 1);
  bf16x8 cur[3], nxt[3];
#pragma unroll
  for (int j = 0; j < 3; ++j)  // b(kk=0, t=0): issued AFTER the two stages
    cur[j] = *(const bf16x8*)&bp[j][0];

  int ab = 0;   // buffer holding stage kk
  int sb = 2;   // buffer to stage kk+2 into
  for (int kk = 0; kk < 16; ++kk) {
    // FIFO oldest-first: vmcnt(7) = stage(kk+1) 4 + last tap's 3 B-prefetches
    asm volatile("s_waitcnt vmcnt(7)" ::: "memory");
    __builtin_amdgcn_s_barrier();
#pragma unroll
    for (int t = 0; t < 9; ++t) {
      {  // prefetch next tap's B (t==8: next kk's tap 0; harmless tail read)
        const int nt  = (t < 8) ? (t + 1) : 0;
        const int nkk = (t < 8) ? kk : kk + 1;
        const size_t bo = (size_t)(nt * 16 + nkk) * 16384;
#pragma unroll
        for (int j = 0; j < 3; ++j)
          nxt[j] = *(const bf16x8*)&bp[j][bo];
      }
      if (t == 1 && kk < 14) STAGE_A(kk + 2, sb);
      const int dy = t / 3, dx = t % 3;
      bf16x8 a[8];
#pragma unroll
      for (int mf = 0; mf < 8; ++mf) {
        const int pb = ((mf >> 1) + dy) * 34 + (mf & 1) * 16 + l15 + dx;
        const int sw = lhi ^ (pb & 3);  // bank swizzle (matches staging)
        a[mf] = *(const bf16x8*)&As[ab][pb * 32 + sw * 8];
      }
      __builtin_amdgcn_s_setprio(1);
#pragma unroll
      for (int c = 0; c < 3; ++c)
#pragma unroll
        for (int mf = 0; mf < 8; ++mf)
          acc[c][mf] = __builtin_amdgcn_mfma_f32_16x16x32_bf16(
              a[mf], cur[c], acc[c][mf], 0, 0, 0);
      __builtin_amdgcn_s_setprio(0);
#pragma unroll
      for (int j = 0; j < 3; ++j) cur[j] = nxt[j];
    }
    ab = (ab == 2) ? 0 : ab + 1;
    sb = (sb == 2) ? 0 : sb + 1;
  }
#undef STAGE_A

  short* outs[3] = {outq, outk, outv};
#pragma unroll
  for (int c = 0; c < 3; ++c) {
    short* out = outs[c];
#pragma unroll
    for (int mf = 0; mf < 8; ++mf)
#pragma unroll
      for (int r = 0; r < 4; ++r) {
        size_t off = ((size_t)n * kHW + sp0 + mf * 16 + lhi * 4 + r) * kC
                     + co0 + w * 16 + l15;
        out[off] = f2bf(acc[c][mf][r]);
      }
  }
}

// ---- conv_o (single conv, 128x128 tile), R10 + A-swizzle ------------------
__global__ __launch_bounds__(256, 3) void conv_o_kernel(
    const short* __restrict__ xin, const short* __restrict__ wtf,
    const float* __restrict__ xres, float* __restrict__ out) {
  __shared__ __align__(16) short As[3][8192];
  const int tid  = threadIdx.x;
  const int lane = tid & 63;
  const int l15  = lane & 15, lhi = lane >> 4;
  const int wv   = tid >> 6;
  const int wm   = wv >> 1, wn = wv & 1;
  const int wbase = tid & 192;

  const int xcd = blockIdx.x & 7;
  const int m   = blockIdx.x >> 3;
  const int co0 = (m >> 5) * 128;
  const int spt = m & 7;
  const int n   = xcd * 4 + ((m >> 3) & 3);
  const int h0  = spt * 4;
  const int sp0 = spt * 128;

  const short* srcA = xin + (size_t)n * (16 * PCH) + (size_t)h0 * (34 * 32);
  const short* bptr = wtf + ((size_t)(co0 >> 4) + wn * 4) * 512 + lane * 8;

  f32x4 acc[4][4];
#pragma unroll
  for (int mf = 0; mf < 4; ++mf)
#pragma unroll
    for (int nf = 0; nf < 4; ++nf)
#pragma unroll
      for (int r = 0; r < 4; ++r) acc[mf][nf][r] = 0.f;

  int ssrc[4];
#pragma unroll
  for (int pass = 0; pass < 4; ++pass) {
    int s = pass * 256 + tid;
    ssrc[pass] = (s & ~3) | ((s & 3) ^ ((s >> 2) & 3));
  }

#define STAGE_A(kk, buf)                                                      \
  {                                                                           \
    const short* gA = srcA + (size_t)(kk) * PCH;                              \
    _Pragma("unroll") for (int pass = 0; pass < 4; ++pass)                    \
        gload_lds16(gA + (size_t)ssrc[pass] * 8,                              \
                    &As[buf][(pass * 256 + wbase) * 8]);                      \
  }

  STAGE_A(0, 0);
  STAGE_A(1, 1);
  bf16x8 cur[4], nxt[4];
#pragma unroll
  for (int j = 0; j < 4; ++j)
    cur[j] = *(const bf16x8*)&bptr[(size_t)j * 512];

  int ab = 0, sb = 2;
  for (int kk = 0; kk < 16; ++kk) {
    asm volatile("s_waitcnt vmcnt(8)" ::: "memory");
    __builtin_amdgcn_s_barrier();
#pragma unroll
    for (int t = 0; t < 9; ++t) {
      {
        const int nt  = (t < 8) ? (t + 1) : 0;
        const int nkk = (t < 8) ? kk : kk + 1;
        const size_t bo = (size_t)(nt * 16 + nkk) * 16384;
#pragma unroll
        for (int j = 0; j < 4; ++j)
          nxt[j] = *(const bf16x8*)&bptr[bo + (size_t)j * 512];
      }
      if (t == 1 && kk < 14) STAGE_A(kk + 2, sb);
      const int dy = t / 3, dx = t % 3;
      bf16x8 a[4];
#pragma unroll
      for (int mf = 0; mf < 4; ++mf) {
        const int pb = (wm * 2 + (mf >> 1) + dy) * 34 + (mf & 1) * 16 + l15 + dx;
        const int sw = lhi ^ (pb & 3);
        a[mf] = *(const bf16x8*)&As[ab][pb * 32 + sw * 8];
      }
      __builtin_amdgcn_s_setprio(1);
#pragma unroll
      for (int mf = 0; mf < 4; ++mf)
#pragma unroll
        for (int nf = 0; nf < 4; ++nf)
          acc[mf][nf] = __builtin_amdgcn_mfma_f32_16x16x32_bf16(
              a[mf], cur[nf], acc[mf][nf], 0, 0, 0);
      __builtin_amdgcn_s_setprio(0);
#pragma unroll
      for (int j = 0; j < 4; ++j) cur[j] = nxt[j];
    }
    ab = (ab == 2) ? 0 : ab + 1;
    sb = (sb == 2) ? 0 : sb + 1;
  }
#undef STAGE_A

  float* T = (float*)&As[0][0];
#pragma unroll
  for (int nf = 0; nf < 4; ++nf) {
    __syncthreads();
    const int coL = wn * 16 + l15;
#pragma unroll
    for (int mf = 0; mf < 4; ++mf)
#pragma unroll
      for (int r = 0; r < 4; ++r)
        T[coL * 129 + wm * 64 + mf * 16 + lhi * 4 + r] = acc[mf][nf][r];
    __syncthreads();
#pragma unroll
    for (int it = 0; it < 16; ++it) {
      int idx = it * 256 + tid;
      int c = idx >> 7, sp = idx & 127;
      int co = co0 + (c >> 4) * 64 + nf * 16 + (c & 15);
      size_t off = ((size_t)n * kC + co) * kHW + sp0 + sp;
      out[off] = T[c * 129 + sp] + xres[off];
    }
  }
}

// ---- MFMA per-pixel attention: QK^T -> softmax -> PV (R11 verified) -------
__global__ __launch_bounds__(256) void attn_mfma_kernel(
    const short* q, const short* __restrict__ k,
    const short* __restrict__ v, short* virt) {
  __shared__ __align__(16) short Qs[32 * 72];  // [i][c 64 + pad 8]
  __shared__ __align__(16) short Ks[32 * 72];  // [j][c 64 + pad 8]
  __shared__ __align__(16) float Ps[32 * 36];  // [i][j 32 + pad 4]
  __shared__ __align__(16) short Vt[64 * 40];  // [cL][j 32 + pad 8], swizzled
  const int p    = blockIdx.x;
  const int tid  = threadIdx.x;
  const int lane = tid & 63;
  const int l15  = lane & 15, lhi = lane >> 4;
  const int w    = tid >> 6;       // wave 0..3
  const int iq   = w >> 1, jq = w & 1;  // S quadrant

  f32x4 accS = {0.f, 0.f, 0.f, 0.f};
  const int si = tid >> 3;
  const int sc = (tid & 7) * 8;
  for (int c0 = 0; c0 < kC; c0 += 64) {
    __syncthreads();
    {
      size_t g = ((size_t)si * kHW + p) * kC + c0 + sc;
      *(bf16x8*)&Qs[si * 72 + sc] = *(const bf16x8*)&q[g];
      *(bf16x8*)&Ks[si * 72 + sc] = *(const bf16x8*)&k[g];
    }
    __syncthreads();
#pragma unroll
    for (int cs = 0; cs < 2; ++cs) {
      bf16x8 aq = *(const bf16x8*)&Qs[(iq * 16 + l15) * 72 + cs * 32 + lhi * 8];
      bf16x8 bk = *(const bf16x8*)&Ks[(jq * 16 + l15) * 72 + cs * 32 + lhi * 8];
      accS = __builtin_amdgcn_mfma_f32_16x16x32_bf16(aq, bk, accS, 0, 0, 0);
    }
  }
  __syncthreads();
  constexpr float scale = 0.044194173824159216f;  // 1/sqrt(512)
#pragma unroll
  for (int r = 0; r < 4; ++r)
    Ps[(iq * 16 + lhi * 4 + r) * 36 + jq * 16 + l15] = accS[r] * scale;
  __syncthreads();

  {
    const int i  = tid >> 3;
    const int j0 = (tid & 7) * 4;
    float a0 = Ps[i * 36 + j0], a1 = Ps[i * 36 + j0 + 1];
    float a2 = Ps[i * 36 + j0 + 2], a3 = Ps[i * 36 + j0 + 3];
    float mx = fmaxf(fmaxf(a0, a1), fmaxf(a2, a3));
    for (int off = 1; off < 8; off <<= 1) mx = fmaxf(mx, __shfl_xor(mx, off));
    float e0 = __expf(a0 - mx), e1 = __expf(a1 - mx);
    float e2 = __expf(a2 - mx), e3 = __expf(a3 - mx);
    float s = e0 + e1 + e2 + e3;
    for (int off = 1; off < 8; off <<= 1) s += __shfl_xor(s, off);
    const float inv = 1.f / s;
    Ps[i * 36 + j0]     = e0 * inv;
    Ps[i * 36 + j0 + 1] = e1 * inv;
    Ps[i * 36 + j0 + 2] = e2 * inv;
    Ps[i * 36 + j0 + 3] = e3 * inv;
  }
  __syncthreads();

  bf16x8 ap[2];
#pragma unroll
  for (int it = 0; it < 2; ++it) {
    const float* pr = &Ps[(it * 16 + l15) * 36 + lhi * 8];
    float4 lo = *(const float4*)pr;
    float4 hi4 = *(const float4*)(pr + 4);
    ap[it][0] = f2bf(lo.x);  ap[it][1] = f2bf(lo.y);
    ap[it][2] = f2bf(lo.z);  ap[it][3] = f2bf(lo.w);
    ap[it][4] = f2bf(hi4.x); ap[it][5] = f2bf(hi4.y);
    ap[it][6] = f2bf(hi4.z); ap[it][7] = f2bf(hi4.w);
  }

  const f32x4 zacc = {0.f, 0.f, 0.f, 0.f};
  for (int c0 = 0; c0 < kC; c0 += 64) {
    __syncthreads();
    {
      const int j = tid >> 3, c8g = tid & 7;
      bf16x8 vvv = *(const bf16x8*)&v[((size_t)j * kHW + p) * kC + c0 + c8g * 8];
#pragma unroll
      for (int jj = 0; jj < 8; ++jj) {
        int c = c8g * 8 + jj;
        int byte = (c * 80 + j * 2) ^ (((c >> 3) & 7) << 4);
        *(short*)((char*)Vt + byte) = vvv[jj];
      }
    }
    __syncthreads();
    {
      const int c = w * 16 + l15;
      const int byte = (c * 80 + lhi * 16) ^ (((c >> 3) & 7) << 4);
      bf16x8 bv = *(const bf16x8*)((const char*)Vt + byte);
#pragma unroll
      for (int it = 0; it < 2; ++it) {
        f32x4 o = __builtin_amdgcn_mfma_f32_16x16x32_bf16(ap[it], bv, zacc, 0, 0, 0);
#pragma unroll
        for (int r = 0; r < 4; ++r)
          virt[((size_t)(it * 16 + lhi * 4 + r) * kHW + p) * kC + c0 + w * 16 + l15] =
              f2bf(o[r]);
      }
    }
  }
}

// ---- GroupNorm(1,C) partial sums: 256 blocks (8 segments x 32 instances) --
__global__ __launch_bounds__(256) void gn_part_kernel(
    const short* __restrict__ virt, float* __restrict__ part) {
  const int i   = blockIdx.x >> 3;
  const int seg = blockIdx.x & 7;
  const short* src = virt + (size_t)i * kHW * kC + (size_t)seg * (kHW * kC / 8);
  float s = 0.f, sq = 0.f;
  for (int idx = threadIdx.x; idx < kHW * kC / 8 / 8; idx += 256) {
    bf16x8 vv = *(const bf16x8*)&src[(size_t)idx * 8];
#pragma unroll
    for (int jj = 0; jj < 8; ++jj) {
      float f = bf2f(vv[jj]);
      s += f;
      sq = fmaf(f, f, sq);
    }
  }
  __shared__ float rs[4], rq[4];
  for (int off = 1; off < 64; off <<= 1) {
    s += __shfl_xor(s, off);
    sq += __shfl_xor(sq, off);
  }
  const int lane = threadIdx.x & 63;
  const int wid = threadIdx.x >> 6;
  if (lane == 0) { rs[wid] = s; rq[wid] = sq; }
  __syncthreads();
  if (threadIdx.x == 0) {
    part[blockIdx.x]       = rs[0] + rs[1] + rs[2] + rs[3];
    part[256 + blockIdx.x] = rq[0] + rq[1] + rq[2] + rq[3];
  }
}

__global__ __launch_bounds__(64) void gn_final_kernel(
    const float* __restrict__ part, float* __restrict__ stats) {
  if (threadIdx.x < 32) {
    float s = 0.f, sq = 0.f;
#pragma unroll
    for (int kq = 0; kq < 8; ++kq) {
      s  += part[threadIdx.x * 8 + kq];
      sq += part[256 + threadIdx.x * 8 + kq];
    }
    constexpr float invn = 1.f / ((float)kHW * kC);
    float mean = s * invn;
    float var = sq * invn - mean * mean;
    stats[threadIdx.x] = mean;
    stats[32 + threadIdx.x] = rsqrtf(var + 1e-5f);
  }
}

// ---- GN apply + affine + ReLU -> chunked-padded bf16 ----------------------
__global__ __launch_bounds__(256) void gn_apply_kernel(
    const short* __restrict__ virt, const float* __restrict__ stats,
    const float* __restrict__ gamma, const float* __restrict__ beta,
    short* __restrict__ vh) {
  const size_t g = (size_t)blockIdx.x * 256 + threadIdx.x;
  const int i    = (int)(g >> 16);
  const int rest = (int)(g & 65535);
  const int p    = rest >> 6;
  const int c8g  = rest & 63;
  const int ci   = c8g * 8;
  const float mean = stats[i];
  const float rstd = stats[32 + i];
  bf16x8 vv = *(const bf16x8*)&virt[((size_t)i * kHW + p) * kC + ci];
  const float4 ga = ((const float4*)gamma)[c8g * 2];
  const float4 gb = ((const float4*)gamma)[c8g * 2 + 1];
  const float4 ba = ((const float4*)beta)[c8g * 2];
  const float4 bb = ((const float4*)beta)[c8g * 2 + 1];
  const float gv[8] = {ga.x, ga.y, ga.z, ga.w, gb.x, gb.y, gb.z, gb.w};
  const float bv[8] = {ba.x, ba.y, ba.z, ba.w, bb.x, bb.y, bb.z, bb.w};
  bf16x8 o;
#pragma unroll
  for (int jj = 0; jj < 8; ++jj) {
    float f = (bf2f(vv[jj]) - mean) * rstd;
    f = fmaxf(fmaf(f, gv[jj], bv[jj]), 0.f);
    o[jj] = f2bf(f);
  }
  const size_t dst =
      (((size_t)i * 16 + (ci >> 5)) * 1156 + (size_t)((p >> 5) + 1) * 34 + (p & 31) + 1) * 32
      + (ci & 31);
  *(bf16x8*)&vh[dst] = o;
}

}  // namespace

extern "C" void kernel_launch(void* const* d_in, const int* in_sizes, int n_in,
                              void* d_out, int out_size, void* d_ws,
                              size_t ws_size, hipStream_t stream) {
  const float* x     = (const float*)d_in[0];
  const float* w_q   = (const float*)d_in[1];
  const float* w_k   = (const float*)d_in[2];
  const float* w_v   = (const float*)d_in[3];
  const float* w_o   = (const float*)d_in[4];
  const float* gamma = (const float*)d_in[5];
  const float* beta  = (const float*)d_in[6];

  short* ws    = (short*)d_ws;
  short* wtf_q = ws;
  short* wtf_k = wtf_q + WTF_ELEMS;
  short* wtf_v = wtf_k + WTF_ELEMS;
  short* wtf_o = wtf_v + WTF_ELEMS;
  short* xh    = wtf_o + WTF_ELEMS;
  short* vh    = xh + XH_ELEMS;
  short* qb    = vh + XH_ELEMS;
  short* kb    = qb + QKV_ELEMS;
  short* vb    = kb + QKV_ELEMS;
  float* stats = (float*)(vb + QKV_ELEMS);  // 64 floats
  float* part  = stats + 64;                // 512 floats
  short* virt  = qb;  // attn writes per-position after reading q
  // zero halos of xh and vh (adjacent regions)
  hipMemsetAsync(xh, 0, (size_t)2 * XH_ELEMS * sizeof(short), stream);

  dim3 wg(16, 16);
  wtf_pack_kernel<<<wg, 256, 0, stream>>>(w_q, wtf_q);
  wtf_pack_kernel<<<wg, 256, 0, stream>>>(w_k, wtf_k);
  wtf_pack_kernel<<<wg, 256, 0, stream>>>(w_v, wtf_v);
  wtf_pack_kernel<<<wg, 256, 0, stream>>>(w_o, wtf_o);

  x2xh_kernel<<<dim3(16, 32, 32), 256, 0, stream>>>(x, xh);

  conv_qkv_kernel<<<2048, 256, 0, stream>>>(xh, wtf_q, wtf_k, wtf_v,
                                            qb, kb, vb);

  attn_mfma_kernel<<<kHW, 256, 0, stream>>>(qb, kb, vb, virt);

  gn_part_kernel<<<256, 256, 0, stream>>>(virt, part);
  gn_final_kernel<<<1, 64, 0, stream>>>(part, stats);
  gn_apply_kernel<<<(int)(QKV_ELEMS / 8 / 256), 256, 0, stream>>>(
      virt, stats, gamma, beta, vh);

  conv_o_kernel<<<1024, 256, 0, stream>>>(vh, wtf_o, x, (float*)d_out);
}

// Round 14
// 563.635 us; speedup vs baseline: 1.0820x; 1.0820x over previous
//
#include <hip/hip_runtime.h>

namespace {

constexpr int kN  = 32;
constexpr int kC  = 512;
constexpr int kH  = 32;
constexpr int kW  = 32;
constexpr int kHW = kH * kW;

// bf16 chunked-padded activation layout: [n][chunk=ci/32][34 rows][34 cols][32 ci]
constexpr int PCH   = 36992;                 // 34*34*32 elems per (n,chunk) plane
constexpr size_t WTF_ELEMS = (size_t)9 * kC * kC;          // 2,359,296 bf16
constexpr size_t XH_ELEMS  = (size_t)kN * 16 * PCH;        // 18,939,904 bf16
constexpr size_t QKV_ELEMS = (size_t)kN * kHW * kC;        // 16,777,216 bf16

using bf16x8 = __attribute__((ext_vector_type(8))) short;
using bf16x4 = __attribute__((ext_vector_type(4))) short;
using f32x4  = __attribute__((ext_vector_type(4))) float;

__device__ __forceinline__ float bf2f(short s) {
  unsigned u = ((unsigned)(unsigned short)s) << 16;
  return __builtin_bit_cast(float, u);
}
__device__ __forceinline__ short f2bf(float f) {
  unsigned u = __builtin_bit_cast(unsigned, f);
  u += 0x7FFFu + ((u >> 16) & 1u);
  return (short)(u >> 16);
}
__device__ __forceinline__ void gload_lds16(const void* g, void* l) {
  __builtin_amdgcn_global_load_lds(
      (const __attribute__((address_space(1))) void*)g,
      (__attribute__((address_space(3))) void*)l, 16, 0, 0);
}

// ---- weight pack (all 4 tensors, z selects): w[co][ci][3][3] f32 ->
//      wtf[t][kk][nnG][lane][8] bf16 ----
__global__ __launch_bounds__(256) void wtf_pack_kernel(
    const float* __restrict__ wq, const float* __restrict__ wk,
    const float* __restrict__ wv, const float* __restrict__ wo,
    short* __restrict__ oq, short* __restrict__ ok,
    short* __restrict__ ov, short* __restrict__ oo) {
  const float* wsrc[4] = {wq, wk, wv, wo};
  short* wdst[4] = {oq, ok, ov, oo};
  const float* w = wsrc[blockIdx.z];
  short* wtf = wdst[blockIdx.z];
  __shared__ float tile[32][289];  // [co][ci*9+t]
  const int co0 = blockIdx.x * 32;
  const int ci0 = blockIdx.y * 32;
  for (int idx = threadIdx.x; idx < 32 * 288; idx += 256) {
    int c = idx % 288, r = idx / 288;
    tile[r][c] = w[(size_t)(co0 + r) * (kC * 9) + (size_t)ci0 * 9 + c];
  }
  __syncthreads();
  const int kkb  = ci0 >> 5;
  const int nnG0 = co0 >> 4;
  for (int g = threadIdx.x; g < 9 * 2 * 64; g += 256) {
    int laneg = g & 63;
    int nnL   = (g >> 6) & 1;
    int t     = g >> 7;  // 0..8
    int hi    = laneg >> 4;
    int coL   = nnL * 16 + (laneg & 15);
    bf16x8 pk;
#pragma unroll
    for (int j = 0; j < 8; ++j) pk[j] = f2bf(tile[coL][(hi * 8 + j) * 9 + t]);
    *(bf16x8*)&wtf[(((size_t)t * 16 + kkb) * 32 + nnG0 + nnL) * 512 + laneg * 8] = pk;
  }
}

// ---- x NCHW f32 -> xh chunked-padded bf16 ---------------------------------
__global__ __launch_bounds__(256) void x2xh_kernel(
    const float* __restrict__ x, short* __restrict__ xh) {
  __shared__ float tile[32][33];  // [w][ci]
  const int ch = blockIdx.x;   // 0..15
  const int h  = blockIdx.y;   // 0..31
  const int n  = blockIdx.z;   // 0..31
  const int w0 = threadIdx.x & 31;
  const int c0 = threadIdx.x >> 5;
#pragma unroll
  for (int pass = 0; pass < 4; ++pass) {
    int cir = pass * 8 + c0;
    tile[w0][cir] = x[(((size_t)n * kC + ch * 32 + cir) * kH + h) * kW + w0];
  }
  __syncthreads();
  const int wv = threadIdx.x >> 3;
  const int g4 = (threadIdx.x & 7) * 4;
  bf16x4 pk;
#pragma unroll
  for (int j = 0; j < 4; ++j) pk[j] = f2bf(tile[wv][g4 + j]);
  *(bf16x4*)&xh[(((size_t)n * 16 + ch) * 1156 + (size_t)(h + 1) * 34 + (wv + 1)) * 32 + g4] = pk;
}

// ---- FUSED q/k/v conv3x3 via MFMA implicit shift-GEMM (R12-measured) ------
// Wave tiling: each wave owns a DISTINCT 16-co quarter x all 128 sp ->
// zero B-load duplication across waves. acc[3][8] f32x4 = 96 VGPR.
__global__ __launch_bounds__(256, 2) void conv_qkv_kernel(
    const short* __restrict__ xin,
    const short* __restrict__ wtq, const short* __restrict__ wtk,
    const short* __restrict__ wtv,
    short* __restrict__ outq, short* __restrict__ outk,
    short* __restrict__ outv) {
  __shared__ __align__(16) short As[3][8192];  // [pos 256][ci 32] bf16, x3
  const int tid  = threadIdx.x;
  const int lane = tid & 63;
  const int l15  = lane & 15, lhi = lane >> 4;
  const int w    = tid >> 6;       // wave 0..3 = co quarter
  const int wbase = tid & 192;

  // 2048 blocks. xcd = bid&7; m = bid>>3 in 0..255:
  //   spt = m&7 (fastest), n = xcd*4 + ((m>>3)&3), co-tile = m>>5 (slowest).
  const int xcd = blockIdx.x & 7;
  const int m   = blockIdx.x >> 3;
  const int co0 = (m >> 5) * 64;
  const int spt = m & 7;
  const int n   = xcd * 4 + ((m >> 3) & 3);
  const int h0  = spt * 4;
  const int sp0 = spt * 128;

  const short* srcA = xin + (size_t)n * (16 * PCH) + (size_t)h0 * (34 * 32);
  const size_t boff = ((size_t)(co0 >> 4) + w) * 512 + lane * 8;
  const short* bp[3] = {wtq + boff, wtk + boff, wtv + boff};

  f32x4 acc[3][8];
#pragma unroll
  for (int c = 0; c < 3; ++c)
#pragma unroll
    for (int mf = 0; mf < 8; ++mf)
#pragma unroll
      for (int r = 0; r < 4; ++r) acc[c][mf][r] = 0.f;

#define STAGE_A(kk, buf)                                                      \
  {                                                                           \
    const short* gA = srcA + (size_t)(kk) * PCH;                              \
    _Pragma("unroll") for (int pass = 0; pass < 4; ++pass)                    \
        gload_lds16(gA + (size_t)(pass * 256 + tid) * 8,                      \
                    &As[buf][(pass * 256 + wbase) * 8]);                      \
  }

  STAGE_A(0, 0);
  STAGE_A(1, 1);
  bf16x8 cur[3], nxt[3];
#pragma unroll
  for (int j = 0; j < 3; ++j)  // b(kk=0, t=0): issued AFTER the two stages
    cur[j] = *(const bf16x8*)&bp[j][0];

  int ab = 0;   // buffer holding stage kk
  int sb = 2;   // buffer to stage kk+2 into
  for (int kk = 0; kk < 16; ++kk) {
    // FIFO oldest-first: vmcnt(7) = stage(kk+1) 4 + last tap's 3 B-prefetches
    asm volatile("s_waitcnt vmcnt(7)" ::: "memory");
    __builtin_amdgcn_s_barrier();
#pragma unroll
    for (int t = 0; t < 9; ++t) {
      {  // prefetch next tap's B (t==8: next kk's tap 0; harmless tail read)
        const int nt  = (t < 8) ? (t + 1) : 0;
        const int nkk = (t < 8) ? kk : kk + 1;
        const size_t bo = (size_t)(nt * 16 + nkk) * 16384;
#pragma unroll
        for (int j = 0; j < 3; ++j)
          nxt[j] = *(const bf16x8*)&bp[j][bo];
      }
      if (t == 1 && kk < 14) STAGE_A(kk + 2, sb);
      const int dy = t / 3, dx = t % 3;
      bf16x8 a[8];
#pragma unroll
      for (int mf = 0; mf < 8; ++mf) {
        const int pb = ((mf >> 1) + dy) * 34 + (mf & 1) * 16 + l15 + dx;
        a[mf] = *(const bf16x8*)&As[ab][pb * 32 + lhi * 8];
      }
      __builtin_amdgcn_s_setprio(1);
#pragma unroll
      for (int c = 0; c < 3; ++c)
#pragma unroll
        for (int mf = 0; mf < 8; ++mf)
          acc[c][mf] = __builtin_amdgcn_mfma_f32_16x16x32_bf16(
              a[mf], cur[c], acc[c][mf], 0, 0, 0);
      __builtin_amdgcn_s_setprio(0);
#pragma unroll
      for (int j = 0; j < 3; ++j) cur[j] = nxt[j];
    }
    ab = (ab == 2) ? 0 : ab + 1;
    sb = (sb == 2) ? 0 : sb + 1;
  }
#undef STAGE_A

  short* outs[3] = {outq, outk, outv};
#pragma unroll
  for (int c = 0; c < 3; ++c) {
    short* out = outs[c];
#pragma unroll
    for (int mf = 0; mf < 8; ++mf)
#pragma unroll
      for (int r = 0; r < 4; ++r) {
        size_t off = ((size_t)n * kHW + sp0 + mf * 16 + lhi * 4 + r) * kC
                     + co0 + w * 16 + l15;
        out[off] = f2bf(acc[c][mf][r]);
      }
  }
}

// ---- conv_o (single conv, 128x128 tile), R12-measured ---------------------
__global__ __launch_bounds__(256, 3) void conv_o_kernel(
    const short* __restrict__ xin, const short* __restrict__ wtf,
    const float* __restrict__ xres, float* __restrict__ out) {
  __shared__ __align__(16) short As[3][8192];
  const int tid  = threadIdx.x;
  const int lane = tid & 63;
  const int l15  = lane & 15, lhi = lane >> 4;
  const int wv   = tid >> 6;
  const int wm   = wv >> 1, wn = wv & 1;
  const int wbase = tid & 192;

  const int xcd = blockIdx.x & 7;
  const int m   = blockIdx.x >> 3;
  const int co0 = (m >> 5) * 128;
  const int spt = m & 7;
  const int n   = xcd * 4 + ((m >> 3) & 3);
  const int h0  = spt * 4;
  const int sp0 = spt * 128;

  const short* srcA = xin + (size_t)n * (16 * PCH) + (size_t)h0 * (34 * 32);
  const short* bptr = wtf + ((size_t)(co0 >> 4) + wn * 4) * 512 + lane * 8;

  f32x4 acc[4][4];
#pragma unroll
  for (int mf = 0; mf < 4; ++mf)
#pragma unroll
    for (int nf = 0; nf < 4; ++nf)
#pragma unroll
      for (int r = 0; r < 4; ++r) acc[mf][nf][r] = 0.f;

#define STAGE_A(kk, buf)                                                      \
  {                                                                           \
    const short* gA = srcA + (size_t)(kk) * PCH;                              \
    _Pragma("unroll") for (int pass = 0; pass < 4; ++pass)                    \
        gload_lds16(gA + (size_t)(pass * 256 + tid) * 8,                      \
                    &As[buf][(pass * 256 + wbase) * 8]);                      \
  }

  STAGE_A(0, 0);
  STAGE_A(1, 1);
  bf16x8 cur[4], nxt[4];
#pragma unroll
  for (int j = 0; j < 4; ++j)
    cur[j] = *(const bf16x8*)&bptr[(size_t)j * 512];

  int ab = 0, sb = 2;
  for (int kk = 0; kk < 16; ++kk) {
    asm volatile("s_waitcnt vmcnt(8)" ::: "memory");
    __builtin_amdgcn_s_barrier();
#pragma unroll
    for (int t = 0; t < 9; ++t) {
      {
        const int nt  = (t < 8) ? (t + 1) : 0;
        const int nkk = (t < 8) ? kk : kk + 1;
        const size_t bo = (size_t)(nt * 16 + nkk) * 16384;
#pragma unroll
        for (int j = 0; j < 4; ++j)
          nxt[j] = *(const bf16x8*)&bptr[bo + (size_t)j * 512];
      }
      if (t == 1 && kk < 14) STAGE_A(kk + 2, sb);
      const int dy = t / 3, dx = t % 3;
      bf16x8 a[4];
#pragma unroll
      for (int mf = 0; mf < 4; ++mf) {
        const int pb = (wm * 2 + (mf >> 1) + dy) * 34 + (mf & 1) * 16 + l15 + dx;
        a[mf] = *(const bf16x8*)&As[ab][pb * 32 + lhi * 8];
      }
      __builtin_amdgcn_s_setprio(1);
#pragma unroll
      for (int mf = 0; mf < 4; ++mf)
#pragma unroll
        for (int nf = 0; nf < 4; ++nf)
          acc[mf][nf] = __builtin_amdgcn_mfma_f32_16x16x32_bf16(
              a[mf], cur[nf], acc[mf][nf], 0, 0, 0);
      __builtin_amdgcn_s_setprio(0);
#pragma unroll
      for (int j = 0; j < 4; ++j) cur[j] = nxt[j];
    }
    ab = (ab == 2) ? 0 : ab + 1;
    sb = (sb == 2) ? 0 : sb + 1;
  }
#undef STAGE_A

  float* T = (float*)&As[0][0];
#pragma unroll
  for (int nf = 0; nf < 4; ++nf) {
    __syncthreads();
    const int coL = wn * 16 + l15;
#pragma unroll
    for (int mf = 0; mf < 4; ++mf)
#pragma unroll
      for (int r = 0; r < 4; ++r)
        T[coL * 129 + wm * 64 + mf * 16 + lhi * 4 + r] = acc[mf][nf][r];
    __syncthreads();
#pragma unroll
    for (int it = 0; it < 16; ++it) {
      int idx = it * 256 + tid;
      int c = idx >> 7, sp = idx & 127;
      int co = co0 + (c >> 4) * 64 + nf * 16 + (c & 15);
      size_t off = ((size_t)n * kC + co) * kHW + sp0 + sp;
      out[off] = T[c * 129 + sp] + xres[off];
    }
  }
}

// ---- MFMA per-pixel attention + fused GN partial sums ---------------------
// R11-verified structure; epilogue accumulates sum/sumsq of the quantized
// virt values and atomically adds 32 per-instance partials per block.
__global__ __launch_bounds__(256) void attn_mfma_kernel(
    const short* q, const short* __restrict__ k,
    const short* __restrict__ v, short* virt, float* __restrict__ gsum) {
  __shared__ __align__(16) short Qs[32 * 72];  // [i][c 64 + pad 8]
  __shared__ __align__(16) short Ks[32 * 72];  // [j][c 64 + pad 8]
  __shared__ __align__(16) float Ps[32 * 36];  // [i][j 32 + pad 4]
  __shared__ __align__(16) short Vt[64 * 40];  // [cL][j 32 + pad 8], swizzled
  const int p    = blockIdx.x;
  const int tid  = threadIdx.x;
  const int lane = tid & 63;
  const int l15  = lane & 15, lhi = lane >> 4;
  const int w    = tid >> 6;       // wave 0..3
  const int iq   = w >> 1, jq = w & 1;  // S quadrant

  f32x4 accS = {0.f, 0.f, 0.f, 0.f};
  const int si = tid >> 3;
  const int sc = (tid & 7) * 8;
  for (int c0 = 0; c0 < kC; c0 += 64) {
    __syncthreads();
    {
      size_t g = ((size_t)si * kHW + p) * kC + c0 + sc;
      *(bf16x8*)&Qs[si * 72 + sc] = *(const bf16x8*)&q[g];
      *(bf16x8*)&Ks[si * 72 + sc] = *(const bf16x8*)&k[g];
    }
    __syncthreads();
#pragma unroll
    for (int cs = 0; cs < 2; ++cs) {
      bf16x8 aq = *(const bf16x8*)&Qs[(iq * 16 + l15) * 72 + cs * 32 + lhi * 8];
      bf16x8 bk = *(const bf16x8*)&Ks[(jq * 16 + l15) * 72 + cs * 32 + lhi * 8];
      accS = __builtin_amdgcn_mfma_f32_16x16x32_bf16(aq, bk, accS, 0, 0, 0);
    }
  }
  __syncthreads();
  constexpr float scale = 0.044194173824159216f;  // 1/sqrt(512)
#pragma unroll
  for (int r = 0; r < 4; ++r)
    Ps[(iq * 16 + lhi * 4 + r) * 36 + jq * 16 + l15] = accS[r] * scale;
  __syncthreads();

  {
    const int i  = tid >> 3;
    const int j0 = (tid & 7) * 4;
    float a0 = Ps[i * 36 + j0], a1 = Ps[i * 36 + j0 + 1];
    float a2 = Ps[i * 36 + j0 + 2], a3 = Ps[i * 36 + j0 + 3];
    float mx = fmaxf(fmaxf(a0, a1), fmaxf(a2, a3));
    for (int off = 1; off < 8; off <<= 1) mx = fmaxf(mx, __shfl_xor(mx, off));
    float e0 = __expf(a0 - mx), e1 = __expf(a1 - mx);
    float e2 = __expf(a2 - mx), e3 = __expf(a3 - mx);
    float s = e0 + e1 + e2 + e3;
    for (int off = 1; off < 8; off <<= 1) s += __shfl_xor(s, off);
    const float inv = 1.f / s;
    Ps[i * 36 + j0]     = e0 * inv;
    Ps[i * 36 + j0 + 1] = e1 * inv;
    Ps[i * 36 + j0 + 2] = e2 * inv;
    Ps[i * 36 + j0 + 3] = e3 * inv;
  }
  __syncthreads();

  bf16x8 ap[2];
#pragma unroll
  for (int it = 0; it < 2; ++it) {
    const float* pr = &Ps[(it * 16 + l15) * 36 + lhi * 8];
    float4 lo = *(const float4*)pr;
    float4 hi4 = *(const float4*)(pr + 4);
    ap[it][0] = f2bf(lo.x);  ap[it][1] = f2bf(lo.y);
    ap[it][2] = f2bf(lo.z);  ap[it][3] = f2bf(lo.w);
    ap[it][4] = f2bf(hi4.x); ap[it][5] = f2bf(hi4.y);
    ap[it][6] = f2bf(hi4.z); ap[it][7] = f2bf(hi4.w);
  }
  __syncthreads();  // all reads of Ps done before epilogue reuses it

  float gs[8], gq2[8];
#pragma unroll
  for (int idx = 0; idx < 8; ++idx) { gs[idx] = 0.f; gq2[idx] = 0.f; }

  const f32x4 zacc = {0.f, 0.f, 0.f, 0.f};
  for (int c0 = 0; c0 < kC; c0 += 64) {
    __syncthreads();
    {
      const int j = tid >> 3, c8g = tid & 7;
      bf16x8 vvv = *(const bf16x8*)&v[((size_t)j * kHW + p) * kC + c0 + c8g * 8];
#pragma unroll
      for (int jj = 0; jj < 8; ++jj) {
        int c = c8g * 8 + jj;
        int byte = (c * 80 + j * 2) ^ (((c >> 3) & 7) << 4);
        *(short*)((char*)Vt + byte) = vvv[jj];
      }
    }
    __syncthreads();
    {
      const int c = w * 16 + l15;
      const int byte = (c * 80 + lhi * 16) ^ (((c >> 3) & 7) << 4);
      bf16x8 bv = *(const bf16x8*)((const char*)Vt + byte);
#pragma unroll
      for (int it = 0; it < 2; ++it) {
        f32x4 o = __builtin_amdgcn_mfma_f32_16x16x32_bf16(ap[it], bv, zacc, 0, 0, 0);
#pragma unroll
        for (int r = 0; r < 4; ++r) {
          short ob = f2bf(o[r]);
          virt[((size_t)(it * 16 + lhi * 4 + r) * kHW + p) * kC + c0 + w * 16 + l15] = ob;
          float fv = bf2f(ob);
          gs[it * 4 + r] += fv;
          gq2[it * 4 + r] = fmaf(fv, fv, gq2[it * 4 + r]);
        }
      }
    }
  }

  // GN partial sums: reduce over the 16 l15-lanes sharing (it,lhi,r)
#pragma unroll
  for (int idx = 0; idx < 8; ++idx)
    for (int off = 1; off < 16; off <<= 1) {
      gs[idx]  += __shfl_xor(gs[idx], off);
      gq2[idx] += __shfl_xor(gq2[idx], off);
    }
  __syncthreads();  // Vt reads done; Ps reuse below
  float* SS = Ps;   // [w][32 inst][2] = 256 floats
  if (l15 == 0) {
#pragma unroll
    for (int idx = 0; idx < 8; ++idx) {
      int it = idx >> 2, r = idx & 3;
      int i = it * 16 + lhi * 4 + r;
      SS[(w * 32 + i) * 2]     = gs[idx];
      SS[(w * 32 + i) * 2 + 1] = gq2[idx];
    }
  }
  __syncthreads();
  if (tid < 32) {
    float s = 0.f, q2 = 0.f;
#pragma unroll
    for (int ww = 0; ww < 4; ++ww) {
      s  += SS[(ww * 32 + tid) * 2];
      q2 += SS[(ww * 32 + tid) * 2 + 1];
    }
    atomicAdd(&gsum[tid], s);
    atomicAdd(&gsum[32 + tid], q2);
  }
}

// ---- GN finalize from fused sums ------------------------------------------
__global__ __launch_bounds__(64) void gn_final_kernel(
    const float* __restrict__ gsum, float* __restrict__ stats) {
  if (threadIdx.x < 32) {
    constexpr float invn = 1.f / ((float)kHW * kC);
    float mean = gsum[threadIdx.x] * invn;
    float var = gsum[32 + threadIdx.x] * invn - mean * mean;
    stats[threadIdx.x] = mean;
    stats[32 + threadIdx.x] = rsqrtf(var + 1e-5f);
  }
}

// ---- GN apply + affine + ReLU -> chunked-padded bf16 ----------------------
__global__ __launch_bounds__(256) void gn_apply_kernel(
    const short* __restrict__ virt, const float* __restrict__ stats,
    const float* __restrict__ gamma, const float* __restrict__ beta,
    short* __restrict__ vh) {
  const size_t g = (size_t)blockIdx.x * 256 + threadIdx.x;
  const int i    = (int)(g >> 16);
  const int rest = (int)(g & 65535);
  const int p    = rest >> 6;
  const int c8g  = rest & 63;
  const int ci   = c8g * 8;
  const float mean = stats[i];
  const float rstd = stats[32 + i];
  bf16x8 vv = *(const bf16x8*)&virt[((size_t)i * kHW + p) * kC + ci];
  const float4 ga = ((const float4*)gamma)[c8g * 2];
  const float4 gb = ((const float4*)gamma)[c8g * 2 + 1];
  const float4 ba = ((const float4*)beta)[c8g * 2];
  const float4 bb = ((const float4*)beta)[c8g * 2 + 1];
  const float gv[8] = {ga.x, ga.y, ga.z, ga.w, gb.x, gb.y, gb.z, gb.w};
  const float bv[8] = {ba.x, ba.y, ba.z, ba.w, bb.x, bb.y, bb.z, bb.w};
  bf16x8 o;
#pragma unroll
  for (int jj = 0; jj < 8; ++jj) {
    float f = (bf2f(vv[jj]) - mean) * rstd;
    f = fmaxf(fmaf(f, gv[jj], bv[jj]), 0.f);
    o[jj] = f2bf(f);
  }
  const size_t dst =
      (((size_t)i * 16 + (ci >> 5)) * 1156 + (size_t)((p >> 5) + 1) * 34 + (p & 31) + 1) * 32
      + (ci & 31);
  *(bf16x8*)&vh[dst] = o;
}

}  // namespace

extern "C" void kernel_launch(void* const* d_in, const int* in_sizes, int n_in,
                              void* d_out, int out_size, void* d_ws,
                              size_t ws_size, hipStream_t stream) {
  const float* x     = (const float*)d_in[0];
  const float* w_q   = (const float*)d_in[1];
  const float* w_k   = (const float*)d_in[2];
  const float* w_v   = (const float*)d_in[3];
  const float* w_o   = (const float*)d_in[4];
  const float* gamma = (const float*)d_in[5];
  const float* beta  = (const float*)d_in[6];

  short* ws    = (short*)d_ws;
  short* wtf_q = ws;
  short* wtf_k = wtf_q + WTF_ELEMS;
  short* wtf_v = wtf_k + WTF_ELEMS;
  short* wtf_o = wtf_v + WTF_ELEMS;
  short* xh    = wtf_o + WTF_ELEMS;
  short* vh    = xh + XH_ELEMS;
  short* qb    = vh + XH_ELEMS;
  short* kb    = qb + QKV_ELEMS;
  short* vb    = kb + QKV_ELEMS;
  float* stats = (float*)(vb + QKV_ELEMS);  // 64 floats
  float* gsum  = stats + 64;                // 64 floats (sum, sumsq)
  short* virt  = qb;  // attn writes per-position after reading q
  // zero halos of xh and vh (adjacent regions) + the fused-GN accumulators
  hipMemsetAsync(xh, 0, (size_t)2 * XH_ELEMS * sizeof(short), stream);
  hipMemsetAsync(gsum, 0, 64 * sizeof(float), stream);

  wtf_pack_kernel<<<dim3(16, 16, 4), 256, 0, stream>>>(
      w_q, w_k, w_v, w_o, wtf_q, wtf_k, wtf_v, wtf_o);

  x2xh_kernel<<<dim3(16, 32, 32), 256, 0, stream>>>(x, xh);

  conv_qkv_kernel<<<2048, 256, 0, stream>>>(xh, wtf_q, wtf_k, wtf_v,
                                            qb, kb, vb);

  attn_mfma_kernel<<<kHW, 256, 0, stream>>>(qb, kb, vb, virt, gsum);

  gn_final_kernel<<<1, 64, 0, stream>>>(gsum, stats);
  gn_apply_kernel<<<(int)(QKV_ELEMS / 8 / 256), 256, 0, stream>>>(
      virt, stats, gamma, beta, vh);

  conv_o_kernel<<<1024, 256, 0, stream>>>(vh, wtf_o, x, (float*)d_out);
}